// Round 3
// baseline (135.420 us; speedup 1.0000x reference)
//
#include <hip/hip_runtime.h>

// Problem constants (fixed by setup_inputs)
#define BB     4
#define HH     640
#define WW     640
#define NLB    10
#define HWSZ   (HH * WW)     // 409600
#define BLK    128           // threads per block (2 waves)
#define PRX    4             // rows per strip (both phases)

// ---- global phase decomposition: interior (mask-free) vs boundary (masked)
// interior strips: bands 1..158 x tiles 1..158 (rows/cols 4..635) -> no padding
#define NIT    158                  // interior tiles per axis
#define NISTR  (NIT * NIT)          // 24964 interior strips per batch
#define NIBPB  196                  // ceil(NISTR/BLK) interior blocks per batch
#define NISLOT (NIBPB * BLK)        // 25088 slots per batch (124 idle guards)
#define GIBLK  (BB * NIBPB)         // 784 interior blocks
// boundary strips: bands {0,159} all tiles + tiles {0,159} bands 1..158
#define NBSTR  636                  // boundary strips per batch
#define NBBPB  5                    // ceil(NBSTR/BLK) boundary blocks per batch
#define NBSLOT (NBBPB * BLK)        // 640 slots per batch
#define GALL   (GIBLK + BB * NBBPB) // 804 global partial slots

// ---- box phase
#define SLOTS  20                   // band slots per box; waves cover slot + w*SLOTS
#define XBLKS  (BB * NLB * SLOTS)   // 800 box blocks
#define NSLOT  (GALL + XBLKS)       // 1604 worker blocks / publish slots

// Publish flag: must differ from the harness workspace poison pattern.
// Not a repeated-byte pattern, not a standard qNaN, not 0xDEADBEEF.
#define MAGICF 0x5EC7A3B9u

// Each publish slot is 4 floats: {sum_in, sum_gr, flag, pad} (16B aligned).

__device__ __forceinline__ float ald(const float* p) {
    return __hip_atomic_load(p, __ATOMIC_RELAXED, __HIP_MEMORY_SCOPE_AGENT);
}

// Reduce (vin, vgr) across a 128-thread block; thread 0 publishes to slot
// with a release-ordered flag (agent scope -> visible across XCD L2s).
__device__ __forceinline__ void publish2(float vin, float vgr,
                                         float* __restrict__ slot) {
    #pragma unroll
    for (int off = 32; off > 0; off >>= 1) {
        vin += __shfl_down(vin, off);
        vgr += __shfl_down(vgr, off);
    }
    __shared__ float s0[2], s1[2];
    const int lane = threadIdx.x & 63;
    const int w    = threadIdx.x >> 6;
    if (lane == 0) { s0[w] = vin; s1[w] = vgr; }
    __syncthreads();
    if (threadIdx.x == 0) {
        __hip_atomic_store(&slot[0], s0[0] + s0[1],
                           __ATOMIC_RELAXED, __HIP_MEMORY_SCOPE_AGENT);
        __hip_atomic_store(&slot[1], s1[0] + s1[1],
                           __ATOMIC_RELAXED, __HIP_MEMORY_SCOPE_AGENT);
        __hip_atomic_store((unsigned*)&slot[2], MAGICF,
                           __ATOMIC_RELEASE, __HIP_MEMORY_SCOPE_AGENT);
    }
}

// Process a 4-wide x PRX-tall strip with top-left center (c0, r0).
// MASK=true : values outside [ry1,ry2) x [cx1,cx2) read as 0 (zero padding ==
//             mask); only centers inside that rectangle accumulate (fmask).
// MASK=false: caller guarantees the full 6x6 footprint is in-bounds and every
//             center is live -> no clamps, no selects (97.5% of global strips).
// m-plane = w0*v + w1*t (sobel of m via linearity).
template<bool MASK>
__device__ __forceinline__ void strip4(const float* __restrict__ v,
                                       const float* __restrict__ t,
                                       const float* __restrict__ g,
                                       int c0, int r0, int ry1, int ry2,
                                       int cx1, int cx2, float w0, float w1,
                                       float& s_in, float& s_gr) {
    // A[plane][row i][col j]; col j=0 is c0-1 .. j=5 is c0+4
    float A[3][PRX + 2][6];
    const float* P[3] = { v, t, g };
    if (MASK) {
        const int c4 = min(max(c0, 0), WW - 4);   // aligned float4 base (safe)
        const int cl = max(c0 - 1, 0);
        const int cr = min(c0 + 4, WW - 1);
        bool okc[6];
        #pragma unroll
        for (int j = 0; j < 6; ++j) {
            const int cc = c0 - 1 + j;
            okc[j] = (cc >= cx1) && (cc < cx2);
        }
        #pragma unroll
        for (int i = 0; i < PRX + 2; ++i) {
            const int rr  = r0 - 1 + i;
            const bool rok = (rr >= ry1) && (rr < ry2);
            const int rb  = min(max(rr, 0), HH - 1) * WW;
            #pragma unroll
            for (int p = 0; p < 3; ++p) {
                const float4 f = *(const float4*)(P[p] + rb + c4);
                const float eL = P[p][rb + cl];
                const float eR = P[p][rb + cr];
                A[p][i][0] = (rok && okc[0]) ? eL  : 0.0f;
                A[p][i][1] = (rok && okc[1]) ? f.x : 0.0f;
                A[p][i][2] = (rok && okc[2]) ? f.y : 0.0f;
                A[p][i][3] = (rok && okc[3]) ? f.z : 0.0f;
                A[p][i][4] = (rok && okc[4]) ? f.w : 0.0f;
                A[p][i][5] = (rok && okc[5]) ? eR  : 0.0f;
            }
        }
        #pragma unroll
        for (int s = 0; s < PRX; ++s) {
            const int rc = r0 + s;                       // center row
            const bool rcin = (rc >= ry1) && (rc < ry2);
            #pragma unroll
            for (int c = 0; c < 4; ++c) {
                float gx[3], gy[3];
                #pragma unroll
                for (int p = 0; p < 3; ++p) {
                    gx[p] = (A[p][s][c + 2] - A[p][s][c])
                          + 2.0f * (A[p][s + 1][c + 2] - A[p][s + 1][c])
                          + (A[p][s + 2][c + 2] - A[p][s + 2][c]);
                    gy[p] = (A[p][s][c] + 2.0f * A[p][s][c + 1] + A[p][s][c + 2])
                          - (A[p][s + 2][c] + 2.0f * A[p][s + 2][c + 1] + A[p][s + 2][c + 2]);
                }
                const float sv  = fabsf(gx[0]) + fabsf(gy[0]);
                const float sg  = fabsf(gx[2]) + fabsf(gy[2]);
                const float gxm = w0 * gx[0] + w1 * gx[1];
                const float gym = w0 * gy[0] + w1 * gy[1];
                const float sm  = fabsf(gxm) + fabsf(gym);
                const float vc  = A[0][s + 1][c + 1];
                const float tc  = A[1][s + 1][c + 1];
                const float gc  = A[2][s + 1][c + 1];
                const float mc  = w0 * vc + w1 * tc;
                const float inb = (rcin && okc[c + 1]) ? 1.0f : 0.0f;
                s_gr += inb * fabsf(sg - fmaxf(sv, sm));
                s_in += inb * fabsf(gc - fmaxf(vc, mc));
            }
        }
    } else {
        // ---- fast path: straight loads, identical expression tree, no selects
        #pragma unroll
        for (int i = 0; i < PRX + 2; ++i) {
            const int rb = (r0 - 1 + i) * WW;
            #pragma unroll
            for (int p = 0; p < 3; ++p) {
                const float4 f = *(const float4*)(P[p] + rb + c0);
                A[p][i][0] = P[p][rb + c0 - 1];
                A[p][i][1] = f.x;
                A[p][i][2] = f.y;
                A[p][i][3] = f.z;
                A[p][i][4] = f.w;
                A[p][i][5] = P[p][rb + c0 + 4];
            }
        }
        #pragma unroll
        for (int s = 0; s < PRX; ++s) {
            #pragma unroll
            for (int c = 0; c < 4; ++c) {
                float gx[3], gy[3];
                #pragma unroll
                for (int p = 0; p < 3; ++p) {
                    gx[p] = (A[p][s][c + 2] - A[p][s][c])
                          + 2.0f * (A[p][s + 1][c + 2] - A[p][s + 1][c])
                          + (A[p][s + 2][c + 2] - A[p][s + 2][c]);
                    gy[p] = (A[p][s][c] + 2.0f * A[p][s][c + 1] + A[p][s][c + 2])
                          - (A[p][s + 2][c] + 2.0f * A[p][s + 2][c + 1] + A[p][s + 2][c + 2]);
                }
                const float sv  = fabsf(gx[0]) + fabsf(gy[0]);
                const float sg  = fabsf(gx[2]) + fabsf(gy[2]);
                const float gxm = w0 * gx[0] + w1 * gx[1];
                const float gym = w0 * gy[0] + w1 * gy[1];
                const float sm  = fabsf(gxm) + fabsf(gym);
                const float vc  = A[0][s + 1][c + 1];
                const float tc  = A[1][s + 1][c + 1];
                const float gc  = A[2][s + 1][c + 1];
                const float mc  = w0 * vc + w1 * tc;
                s_gr += fabsf(sg - fmaxf(sv, sm));
                s_in += fabsf(gc - fmaxf(vc, mc));
            }
        }
    }
}

// ---------------- Single fused kernel ----------------
// blocks [0, GIBLK):        global interior strips (mask-free fast path)
// blocks [GIBLK, GALL):     global boundary strips (masked path)
// blocks [GALL, NSLOT):     box bands (masked path)
// block  NSLOT:             finalizer — spins on the 1604 publish flags,
//                           then computes all 7 outputs (old kfin logic).
// Every worker block writes its dedicated slot -> no workspace init needed;
// the poison fill each iteration resets the flags to non-MAGICF garbage.
__global__ __launch_bounds__(BLK) void kmain(const float* __restrict__ vis,
                                             const float* __restrict__ th,
                                             const float* __restrict__ gen,
                                             const int* __restrict__ label,
                                             float* __restrict__ slots,
                                             const float* __restrict__ bptr,
                                             const float* __restrict__ cptr,
                                             float* __restrict__ out) {
    const int t = threadIdx.x;
    const unsigned bx = blockIdx.x;
    float s_in = 0.0f, s_gr = 0.0f;
    if (bx < GIBLK) {
        // ---- global interior: gi -> (batch, band, xt), bands/tiles 1..158
        const int gi = bx * BLK + t;
        const int b  = gi / NISLOT;
        const int r  = gi - b * NISLOT;
        if (r < NISTR) {
            const int xt   = 1 + r % NIT;
            const int band = 1 + r / NIT;
            strip4<false>(vis + b * HWSZ, th + b * HWSZ, gen + b * HWSZ,
                          4 * xt, 4 * band, 0, HH, 0, WW, 0.5f, 0.5f,
                          s_in, s_gr);
        }
        publish2(s_in, s_gr, slots + bx * 4);
    } else if (bx < GALL) {
        // ---- global boundary: 636 strips/batch on the image frame
        const int q = (bx - GIBLK) * BLK + t;
        const int b = q / NBSLOT;
        const int r = q - b * NBSLOT;
        if (r < NBSTR) {
            int band, xt;
            if (r < 160)      { band = 0;   xt = r; }
            else if (r < 320) { band = 159; xt = r - 160; }
            else if (r < 478) { xt = 0;     band = 1 + (r - 320); }
            else              { xt = 159;   band = 1 + (r - 478); }
            strip4<true>(vis + b * HWSZ, th + b * HWSZ, gen + b * HWSZ,
                         4 * xt, 4 * band, 0, HH, 0, WW, 0.5f, 0.5f,
                         s_in, s_gr);
        }
        publish2(s_in, s_gr, slots + bx * 4);
    } else if (bx < NSLOT) {
        // ---- box phase: block = (box, slot); wave w covers bands slot+w*SLOTS,
        //      stepping 2*SLOTS bands; 64-lane x 4-col (256-wide) column tiles.
        const int q    = bx - GALL;
        const int box  = q / SLOTS;
        const int slot = q % SLOTS;
        const int b    = box / NLB;
        const int w    = t >> 6;
        const int lane = t & 63;
        const int* lb  = label + box * 5;
        const int x1 = lb[1], y1 = lb[2], x2 = lb[3], y2 = lb[4];
        const int x1a = x1 & ~3;   // aligned start; cols < x1 are masked
        const float* v  = vis + b * HWSZ;
        const float* tp = th  + b * HWSZ;
        const float* g  = gen + b * HWSZ;
        for (int r0 = y1 + (slot + w * SLOTS) * PRX; r0 < y2;
             r0 += 2 * SLOTS * PRX)
            for (int cb = x1a; cb < x2; cb += 64 * 4) {
                const int c0 = cb + 4 * lane;
                // lanes fully right of the box contribute exactly 0 -> skip
                if (c0 < x2)
                    strip4<true>(v, tp, g, c0, r0, y1, y2, x1, x2,
                                 0.3f, 0.7f, s_in, s_gr);
            }
        publish2(s_in, s_gr, slots + bx * 4);
    } else {
        // ================= finalizer block =================
        // Spin until every worker slot's flag is MAGICF (relaxed agent loads),
        // then fence; all subsequent value reads are agent-scope atomic
        // loads -> coherent across XCD L2s.
        for (int i = t; i < NSLOT; i += BLK) {
            const unsigned* fl = (const unsigned*)(slots + i * 4 + 2);
            while (__hip_atomic_load(fl, __ATOMIC_RELAXED,
                                     __HIP_MEMORY_SCOPE_AGENT) != MAGICF) {
                __builtin_amdgcn_s_sleep(1);
            }
        }
        __syncthreads();
        __threadfence();   // device-scope fence: orders flag spin before reads

        __shared__ float Sin[BB], Sgr[BB];
        __shared__ float Ls[BB * NLB], L1[BB * NLB];
        __shared__ float r0s[2], r1s[2];

        // ---- global partial reduce, one batch at a time (all 128 threads)
        for (int b = 0; b < BB; ++b) {
            float a = 0.0f, gr = 0.0f;
            for (int j = t; j < NIBPB; j += BLK) {       // 196 slots, 2 rounds
                const float* s = slots + (b * NIBPB + j) * 4;
                a  += ald(s + 0);
                gr += ald(s + 1);
            }
            if (t < NBBPB) {                              // 5 boundary slots
                const float* s = slots + (GIBLK + b * NBBPB + t) * 4;
                a  += ald(s + 0);
                gr += ald(s + 1);
            }
            #pragma unroll
            for (int off = 32; off > 0; off >>= 1) {
                a  += __shfl_down(a, off);
                gr += __shfl_down(gr, off);
            }
            if ((t & 63) == 0) { r0s[t >> 6] = a; r1s[t >> 6] = gr; }
            __syncthreads();
            if (t == 0) { Sin[b] = r0s[0] + r0s[1]; Sgr[b] = r1s[0] + r1s[1]; }
            __syncthreads();
        }

        // ---- per-box reduce over band slots + area/valid normalization
        if (t < BB * NLB) {
            float si = 0.0f, sg = 0.0f;
            #pragma unroll
            for (int s = 0; s < SLOTS; ++s) {
                const float* p = slots + (GALL + t * SLOTS + s) * 4;
                si += ald(p + 0);
                sg += ald(p + 1);
            }
            const int* lb = label + t * 5;
            const int x1 = lb[1], y1 = lb[2], x2 = lb[3], y2 = lb[4];
            const bool valid = !((x1 == 0) && (y1 == 0) && (x2 == 0) && (y2 == 0));
            const float area = (float)((y2 - y1) * (x2 - x1));  // * C, C==1
            const float safe_area = fmaxf(area, 1.0f);
            const float vv = valid ? 1.0f : 0.0f;
            Ls[t] = sg / safe_area * vv;   // Lssim: gradient term
            L1[t] = si / safe_area * vv;   // L1loss: intensity term
        }
        __syncthreads();
        if (t < BB) {
            const float alpha = bptr[0];
            const float beta  = cptr[0];
            float cnt = 0.0f, sls = 0.0f, slin = 0.0f;
            for (int nl = 0; nl < NLB; nl++) {
                const float a = Ls[t * NLB + nl];
                const float l = L1[t * NLB + nl];
                if (a != 0.0f || l != 0.0f) cnt += 1.0f;
                sls  += a;
                slin += l;
            }
            const float safe_cnt = fmaxf(cnt, 1.0f);
            const float ls  = (cnt > 0.0f) ? (sls  / safe_cnt) : 0.0f;
            const float lin = (cnt > 0.0f) ? (slin / safe_cnt) : 0.0f;
            const float loss_label = (1.0f - beta) * ls + beta * lin;
            const float loss_in    = Sin[t] * (1.0f / (float)HWSZ);
            const float loss_grad  = Sgr[t] * (1.0f / (float)HWSZ);
            const float loss_global = alpha * loss_in + (1.0f - alpha) * loss_grad;
            out[0      + t] = 0.0f;          // loss_ss
            out[BB     + t] = loss_global;
            out[2 * BB + t] = loss_label;
            out[3 * BB + t] = loss_in;
            out[4 * BB + t] = loss_grad;
            out[5 * BB + t] = ls;
            out[6 * BB + t] = lin;
        }
    }
}

extern "C" void kernel_launch(void* const* d_in, const int* in_sizes, int n_in,
                              void* d_out, int out_size, void* d_ws, size_t ws_size,
                              hipStream_t stream) {
    const float* bptr  = (const float*)d_in[0];
    const float* cptr  = (const float*)d_in[1];
    const float* vis   = (const float*)d_in[2];
    // d_in[3] = image_ir (unused by the reference)
    const float* gen   = (const float*)d_in[4];
    const int*   label = (const int*)d_in[5];
    const float* th    = (const float*)d_in[6];
    float* out = (float*)d_out;

    float* slots = (float*)d_ws;   // NSLOT * 4 floats (~25.7 KB)
    // Every slot is written unconditionally by its worker block; flags are
    // reset to poison by the harness fill each iteration -> no memset needed.

    kmain<<<NSLOT + 1, BLK, 0, stream>>>(vis, th, gen, label, slots,
                                         bptr, cptr, out);
}

// Round 4
// 122.085 us; speedup vs baseline: 1.1092x; 1.1092x over previous
//
#include <hip/hip_runtime.h>

// Problem constants (fixed by setup_inputs)
#define BB     4
#define HH     640
#define WW     640
#define NLB    10
#define HWSZ   (HH * WW)     // 409600
#define BLK    128           // threads per block (2 waves)
#define PRX    4             // rows per strip (both phases)

// ---- global phase decomposition: interior (mask-free) vs boundary (masked)
// interior strips: bands 1..158 x tiles 1..158 (rows/cols 4..635) -> no padding
#define NIT    158                  // interior tiles per axis
#define NISTR  (NIT * NIT)          // 24964 interior strips per batch
#define NIBPB  196                  // ceil(NISTR/BLK) interior blocks per batch
#define NISLOT (NIBPB * BLK)        // 25088 slots per batch (124 idle guards)
#define GIBLK  (BB * NIBPB)         // 784 interior blocks
// boundary strips: bands {0,159} all tiles + tiles {0,159} bands 1..158
#define NBSTR  636                  // boundary strips per batch
#define NBBPB  5                    // ceil(NBSTR/BLK) boundary blocks per batch
#define NBSLOT (NBBPB * BLK)        // 640 slots per batch
#define GALL   (GIBLK + BB * NBBPB) // 804 global partial slots

// ---- box phase
#define SLOTS  20                   // band slots per box; waves cover slot + w*SLOTS
#define XBLKS  (BB * NLB * SLOTS)   // 800 box blocks

// Reduce (vin, vgr) across a 128-thread block; thread 0 stores to dst[0..1].
__device__ __forceinline__ void reduce2_write(float vin, float vgr,
                                              float* __restrict__ dst) {
    #pragma unroll
    for (int off = 32; off > 0; off >>= 1) {
        vin += __shfl_down(vin, off);
        vgr += __shfl_down(vgr, off);
    }
    __shared__ float s0[2], s1[2];
    const int lane = threadIdx.x & 63;
    const int w    = threadIdx.x >> 6;
    if (lane == 0) { s0[w] = vin; s1[w] = vgr; }
    __syncthreads();
    if (threadIdx.x == 0) {
        dst[0] = s0[0] + s0[1];
        dst[1] = s1[0] + s1[1];
    }
}

// Process a 4-wide x PRX-tall strip with top-left center (c0, r0).
// Halo columns (c0-1, c0+4) come from neighbor LANES via shuffle when
// haveL/haveR say the neighbor lane holds the adjacent tile of the SAME rows;
// otherwise a (rare, exec-masked) scalar fallback load is used.
// MASK=true : values outside [ry1,ry2) x [cx1,cx2) read as 0 (zero padding ==
//             mask); only centers inside that rectangle accumulate (fmask).
// MASK=false: caller guarantees the full 6x6 footprint is in-bounds and every
//             center is live -> no clamps, no selects.
// m-plane = w0*v + w1*t (sobel of m via linearity).
template<bool MASK>
__device__ __forceinline__ void strip4(const float* __restrict__ v,
                                       const float* __restrict__ t,
                                       const float* __restrict__ g,
                                       int c0, int r0, int ry1, int ry2,
                                       int cx1, int cx2, float w0, float w1,
                                       bool haveL, bool haveR,
                                       float& s_in, float& s_gr) {
    // A[plane][row i][col j]; col j=0 is c0-1 .. j=5 is c0+4
    float A[3][PRX + 2][6];
    const float* P[3] = { v, t, g };
    if (MASK) {
        // NOTE: in the box phase c0 is always in [0, WW-4] so c4 == c0 and the
        // neighbor-lane shuffle yields exactly columns c0-1 / c0+4.
        const int c4 = min(max(c0, 0), WW - 4);   // aligned float4 base (safe)
        const int cl = max(c0 - 1, 0);
        const int cr = min(c0 + 4, WW - 1);
        bool okc[6];
        #pragma unroll
        for (int j = 0; j < 6; ++j) {
            const int cc = c0 - 1 + j;
            okc[j] = (cc >= cx1) && (cc < cx2);
        }
        #pragma unroll
        for (int i = 0; i < PRX + 2; ++i) {
            const int rr  = r0 - 1 + i;
            const bool rok = (rr >= ry1) && (rr < ry2);
            const int rb  = min(max(rr, 0), HH - 1) * WW;
            #pragma unroll
            for (int p = 0; p < 3; ++p) {
                const float4 f = *(const float4*)(P[p] + rb + c4);
                float eL = __shfl_up(f.w, 1);     // neighbor lane's col c0-1
                float eR = __shfl_down(f.x, 1);   // neighbor lane's col c0+4
                if (!haveL) eL = P[p][rb + cl];
                if (!haveR) eR = P[p][rb + cr];
                A[p][i][0] = (rok && okc[0]) ? eL  : 0.0f;
                A[p][i][1] = (rok && okc[1]) ? f.x : 0.0f;
                A[p][i][2] = (rok && okc[2]) ? f.y : 0.0f;
                A[p][i][3] = (rok && okc[3]) ? f.z : 0.0f;
                A[p][i][4] = (rok && okc[4]) ? f.w : 0.0f;
                A[p][i][5] = (rok && okc[5]) ? eR  : 0.0f;
            }
        }
        #pragma unroll
        for (int s = 0; s < PRX; ++s) {
            const int rc = r0 + s;                       // center row
            const bool rcin = (rc >= ry1) && (rc < ry2);
            #pragma unroll
            for (int c = 0; c < 4; ++c) {
                float gx[3], gy[3];
                #pragma unroll
                for (int p = 0; p < 3; ++p) {
                    gx[p] = (A[p][s][c + 2] - A[p][s][c])
                          + 2.0f * (A[p][s + 1][c + 2] - A[p][s + 1][c])
                          + (A[p][s + 2][c + 2] - A[p][s + 2][c]);
                    gy[p] = (A[p][s][c] + 2.0f * A[p][s][c + 1] + A[p][s][c + 2])
                          - (A[p][s + 2][c] + 2.0f * A[p][s + 2][c + 1] + A[p][s + 2][c + 2]);
                }
                const float sv  = fabsf(gx[0]) + fabsf(gy[0]);
                const float sg  = fabsf(gx[2]) + fabsf(gy[2]);
                const float gxm = w0 * gx[0] + w1 * gx[1];
                const float gym = w0 * gy[0] + w1 * gy[1];
                const float sm  = fabsf(gxm) + fabsf(gym);
                const float vc  = A[0][s + 1][c + 1];
                const float tc  = A[1][s + 1][c + 1];
                const float gc  = A[2][s + 1][c + 1];
                const float mc  = w0 * vc + w1 * tc;
                const float inb = (rcin && okc[c + 1]) ? 1.0f : 0.0f;
                s_gr += inb * fabsf(sg - fmaxf(sv, sm));
                s_in += inb * fabsf(gc - fmaxf(vc, mc));
            }
        }
    } else {
        // ---- fast path: straight loads + shuffle halos, no clamps/selects
        #pragma unroll
        for (int i = 0; i < PRX + 2; ++i) {
            const int rb = (r0 - 1 + i) * WW;
            #pragma unroll
            for (int p = 0; p < 3; ++p) {
                const float4 f = *(const float4*)(P[p] + rb + c0);
                float eL = __shfl_up(f.w, 1);
                float eR = __shfl_down(f.x, 1);
                if (!haveL) eL = P[p][rb + c0 - 1];
                if (!haveR) eR = P[p][rb + c0 + 4];
                A[p][i][0] = eL;
                A[p][i][1] = f.x;
                A[p][i][2] = f.y;
                A[p][i][3] = f.z;
                A[p][i][4] = f.w;
                A[p][i][5] = eR;
            }
        }
        #pragma unroll
        for (int s = 0; s < PRX; ++s) {
            #pragma unroll
            for (int c = 0; c < 4; ++c) {
                float gx[3], gy[3];
                #pragma unroll
                for (int p = 0; p < 3; ++p) {
                    gx[p] = (A[p][s][c + 2] - A[p][s][c])
                          + 2.0f * (A[p][s + 1][c + 2] - A[p][s + 1][c])
                          + (A[p][s + 2][c + 2] - A[p][s + 2][c]);
                    gy[p] = (A[p][s][c] + 2.0f * A[p][s][c + 1] + A[p][s][c + 2])
                          - (A[p][s + 2][c] + 2.0f * A[p][s + 2][c + 1] + A[p][s + 2][c + 2]);
                }
                const float sv  = fabsf(gx[0]) + fabsf(gy[0]);
                const float sg  = fabsf(gx[2]) + fabsf(gy[2]);
                const float gxm = w0 * gx[0] + w1 * gx[1];
                const float gym = w0 * gy[0] + w1 * gy[1];
                const float sm  = fabsf(gxm) + fabsf(gym);
                const float vc  = A[0][s + 1][c + 1];
                const float tc  = A[1][s + 1][c + 1];
                const float gc  = A[2][s + 1][c + 1];
                const float mc  = w0 * vc + w1 * tc;
                s_gr += fabsf(sg - fmaxf(sv, sm));
                s_in += fabsf(gc - fmaxf(vc, mc));
            }
        }
    }
}

// ---------------- Fused main kernel ----------------
// blocks [0, GIBLK):          global interior strips (mask-free fast path)
// blocks [GIBLK, GALL):       global boundary strips (masked path)
// blocks [GALL, GALL+XBLKS):  box bands (masked path)
// Every block writes its 2 partial sums to a dedicated slot (no init needed).
__global__ __launch_bounds__(BLK) void kmain(const float* __restrict__ vis,
                                             const float* __restrict__ th,
                                             const float* __restrict__ gen,
                                             const int* __restrict__ label,
                                             float* __restrict__ gpart,
                                             float* __restrict__ xpart) {
    const int t = threadIdx.x;
    const unsigned bx = blockIdx.x;
    const int lane = t & 63;
    float s_in = 0.0f, s_gr = 0.0f;
    if (bx < GIBLK) {
        // ---- global interior: gi -> (batch, band, xt), bands/tiles 1..158
        // Consecutive lanes hold consecutive xt within a band (wrap at NIT),
        // so halos come from neighbor lanes except at wrap/wave edges.
        const int gi = bx * BLK + t;
        const int b  = gi / NISLOT;
        const int r  = gi - b * NISLOT;
        if (r < NISTR) {
            const int xt   = 1 + r % NIT;
            const int band = 1 + r / NIT;
            const bool haveL = (lane > 0)  && (r % NIT != 0);
            const bool haveR = (lane < 63) && (r % NIT != NIT - 1);
            strip4<false>(vis + b * HWSZ, th + b * HWSZ, gen + b * HWSZ,
                          4 * xt, 4 * band, 0, HH, 0, WW, 0.5f, 0.5f,
                          haveL, haveR, s_in, s_gr);
        }
        reduce2_write(s_in, s_gr, gpart + bx * 2);
    } else if (bx < GALL) {
        // ---- global boundary: 636 strips/batch on the image frame
        const int q = (bx - GIBLK) * BLK + t;
        const int b = q / NBSLOT;
        const int r = q - b * NBSLOT;
        if (r < NBSTR) {
            int band, xt;
            if (r < 160)      { band = 0;   xt = r; }
            else if (r < 320) { band = 159; xt = r - 160; }
            else if (r < 478) { xt = 0;     band = 1 + (r - 320); }
            else              { xt = 159;   band = 1 + (r - 478); }
            strip4<true>(vis + b * HWSZ, th + b * HWSZ, gen + b * HWSZ,
                         4 * xt, 4 * band, 0, HH, 0, WW, 0.5f, 0.5f,
                         false, false, s_in, s_gr);
        }
        reduce2_write(s_in, s_gr, gpart + bx * 2);
    } else {
        // ---- box phase: block = (box, slot); wave w covers bands slot+w*SLOTS,
        //      stepping 2*SLOTS bands; 64-lane x 4-col (256-wide) column tiles.
        //      Lanes are column-consecutive -> shuffle halos; neighbor lane is
        //      active exactly when its c0 < x2, matching haveL/haveR below.
        const int q    = bx - GALL;
        const int box  = q / SLOTS;
        const int slot = q % SLOTS;
        const int b    = box / NLB;
        const int w    = t >> 6;
        const int* lb  = label + box * 5;
        const int x1 = lb[1], y1 = lb[2], x2 = lb[3], y2 = lb[4];
        const int x1a = x1 & ~3;   // aligned start; cols < x1 are masked
        const float* v  = vis + b * HWSZ;
        const float* tp = th  + b * HWSZ;
        const float* g  = gen + b * HWSZ;
        for (int r0 = y1 + (slot + w * SLOTS) * PRX; r0 < y2;
             r0 += 2 * SLOTS * PRX)
            for (int cb = x1a; cb < x2; cb += 64 * 4) {
                const int c0 = cb + 4 * lane;
                // lanes fully right of the box contribute exactly 0 -> skip
                if (c0 < x2) {
                    const bool haveL = (lane > 0);
                    const bool haveR = (lane < 63) && (c0 + 4 < x2);
                    strip4<true>(v, tp, g, c0, r0, y1, y2, x1, x2,
                                 0.3f, 0.7f, haveL, haveR, s_in, s_gr);
                }
            }
        reduce2_write(s_in, s_gr, xpart + q * 2);
    }
}

// ---------------- Finalize: reduce partials, compute all 7 outputs ----------
// out layout (flat, return order): loss_ss[4], loss_global[4], loss_label[4],
//                                  loss_in[4], loss_grad[4], ls[4], lin[4]
__global__ __launch_bounds__(256) void kfin(const float* __restrict__ gpart,
                                            const float* __restrict__ xpart,
                                            const int* __restrict__ label,
                                            const float* __restrict__ bptr,
                                            const float* __restrict__ cptr,
                                            float* __restrict__ out) {
    const int t = threadIdx.x;
    __shared__ float Sin[BB], Sgr[BB];
    __shared__ float Ls[BB * NLB], L1[BB * NLB];
    // global partial reduce: wave w = batch w
    //   interior blocks [w*NIBPB, (w+1)*NIBPB) + boundary [GIBLK+w*NBBPB, +NBBPB)
    {
        const int w = t >> 6, l = t & 63;
        float a = 0.0f, gr = 0.0f;
        for (int j = l; j < NIBPB; j += 64) {
            a  += gpart[(w * NIBPB + j) * 2 + 0];
            gr += gpart[(w * NIBPB + j) * 2 + 1];
        }
        if (l < NBBPB) {
            const int idx = GIBLK + w * NBBPB + l;
            a  += gpart[idx * 2 + 0];
            gr += gpart[idx * 2 + 1];
        }
        #pragma unroll
        for (int off = 32; off > 0; off >>= 1) {
            a  += __shfl_down(a, off);
            gr += __shfl_down(gr, off);
        }
        if (l == 0) { Sin[w] = a; Sgr[w] = gr; }
    }
    // per-box reduce over band slots + area/valid normalization
    if (t < BB * NLB) {
        float si = 0.0f, sg = 0.0f;
        #pragma unroll
        for (int s = 0; s < SLOTS; ++s) {
            si += xpart[(t * SLOTS + s) * 2 + 0];
            sg += xpart[(t * SLOTS + s) * 2 + 1];
        }
        const int* lb = label + t * 5;
        const int x1 = lb[1], y1 = lb[2], x2 = lb[3], y2 = lb[4];
        const bool valid = !((x1 == 0) && (y1 == 0) && (x2 == 0) && (y2 == 0));
        const float area = (float)((y2 - y1) * (x2 - x1));  // * C, C==1
        const float safe_area = fmaxf(area, 1.0f);
        const float vv = valid ? 1.0f : 0.0f;
        Ls[t] = sg / safe_area * vv;   // Lssim: gradient term
        L1[t] = si / safe_area * vv;   // L1loss: intensity term
    }
    __syncthreads();
    if (t < BB) {
        const float alpha = bptr[0];
        const float beta  = cptr[0];
        float cnt = 0.0f, sls = 0.0f, slin = 0.0f;
        for (int nl = 0; nl < NLB; nl++) {
            const float a = Ls[t * NLB + nl];
            const float l = L1[t * NLB + nl];
            if (a != 0.0f || l != 0.0f) cnt += 1.0f;
            sls  += a;
            slin += l;
        }
        const float safe_cnt = fmaxf(cnt, 1.0f);
        const float ls  = (cnt > 0.0f) ? (sls  / safe_cnt) : 0.0f;
        const float lin = (cnt > 0.0f) ? (slin / safe_cnt) : 0.0f;
        const float loss_label = (1.0f - beta) * ls + beta * lin;
        const float loss_in    = Sin[t] * (1.0f / (float)HWSZ);
        const float loss_grad  = Sgr[t] * (1.0f / (float)HWSZ);
        const float loss_global = alpha * loss_in + (1.0f - alpha) * loss_grad;
        out[0      + t] = 0.0f;          // loss_ss
        out[BB     + t] = loss_global;
        out[2 * BB + t] = loss_label;
        out[3 * BB + t] = loss_in;
        out[4 * BB + t] = loss_grad;
        out[5 * BB + t] = ls;
        out[6 * BB + t] = lin;
    }
}

extern "C" void kernel_launch(void* const* d_in, const int* in_sizes, int n_in,
                              void* d_out, int out_size, void* d_ws, size_t ws_size,
                              hipStream_t stream) {
    const float* bptr  = (const float*)d_in[0];
    const float* cptr  = (const float*)d_in[1];
    const float* vis   = (const float*)d_in[2];
    // d_in[3] = image_ir (unused by the reference)
    const float* gen   = (const float*)d_in[4];
    const int*   label = (const int*)d_in[5];
    const float* th    = (const float*)d_in[6];
    float* out = (float*)d_out;

    float* gpart = (float*)d_ws;            // GALL*2 floats
    float* xpart = gpart + GALL * 2;        // XBLKS*2 floats
    // Every slot is written unconditionally by its block — no memset needed.

    kmain<<<GALL + XBLKS, BLK, 0, stream>>>(vis, th, gen, label, gpart, xpart);
    kfin<<<1, 256, 0, stream>>>(gpart, xpart, label, bptr, cptr, out);
}

// Round 5
// 99.547 us; speedup vs baseline: 1.3604x; 1.2264x over previous
//
#include <hip/hip_runtime.h>

// Problem constants (fixed by setup_inputs)
#define BB     4
#define HH     640
#define WW     640
#define NLB    10
#define HWSZ   (HH * WW)     // 409600
#define BLK    128           // threads per block (2 waves)
#define PRX    4             // rows per strip (both phases)

// ---- global phase decomposition: interior (mask-free) vs boundary (masked)
// interior strips: bands 1..158 x tiles 1..158 (rows/cols 4..635) -> no padding
#define NIT    158                  // interior tiles per axis
#define NISTR  (NIT * NIT)          // 24964 interior strips per batch
#define NIBPB  196                  // ceil(NISTR/BLK) interior blocks per batch
#define NISLOT (NIBPB * BLK)        // 25088 slots per batch (124 idle guards)
#define GIBLK  (BB * NIBPB)         // 784 interior blocks
// boundary strips: bands {0,159} all tiles + tiles {0,159} bands 1..158
#define NBSTR  636                  // boundary strips per batch
#define NBBPB  5                    // ceil(NBSTR/BLK) boundary blocks per batch
#define NBSLOT (NBBPB * BLK)        // 640 slots per batch
#define GALL   (GIBLK + BB * NBBPB) // 804 global partial slots

// ---- box phase
#define SLOTS  20                   // band slots per box; waves cover slot + w*SLOTS
#define XBLKS  (BB * NLB * SLOTS)   // 800 box blocks

// ---- XCD-contiguous swizzle (bijective for NWG % 8 != 0, m204 form)
// HW round-robins blockIdx across the 8 XCD L2s; logical block order walks
// bands contiguously, so remap: XCD k owns a CONTIGUOUS logical chunk ->
// vertically adjacent bands (which share 2 of 6 fetched halo rows) hit the
// SAME L2 instead of fetching those rows from HBM once per XCD.
#define NWG    (GALL + XBLKS)       // 1604
#define NXCD   8
#define QW     (NWG / NXCD)         // 200
#define RW     (NWG % NXCD)         // 4

// Reduce (vin, vgr) across a 128-thread block; thread 0 stores to dst[0..1].
__device__ __forceinline__ void reduce2_write(float vin, float vgr,
                                              float* __restrict__ dst) {
    #pragma unroll
    for (int off = 32; off > 0; off >>= 1) {
        vin += __shfl_down(vin, off);
        vgr += __shfl_down(vgr, off);
    }
    __shared__ float s0[2], s1[2];
    const int lane = threadIdx.x & 63;
    const int w    = threadIdx.x >> 6;
    if (lane == 0) { s0[w] = vin; s1[w] = vgr; }
    __syncthreads();
    if (threadIdx.x == 0) {
        dst[0] = s0[0] + s0[1];
        dst[1] = s1[0] + s1[1];
    }
}

// Process a 4-wide x PRX-tall strip with top-left center (c0, r0).
// Values outside [ry1,ry2) x [cx1,cx2) read as 0 (zero padding == mask).
// Only centers inside that rectangle accumulate (fmask).
// MASK=false: caller guarantees the full 6x6 footprint is in-bounds and every
//             center is live -> no clamps, no selects (97.5% of global strips).
// All halo loads are plain scalar loads: 54 INDEPENDENT VMEM ops per thread,
// issued back-to-back -> max memory-level parallelism (R4's shuffle variant
// serialized these behind per-row waitcnts and cost +20 us).
// m-plane = w0*v + w1*t (sobel of m via linearity).
template<bool MASK>
__device__ __forceinline__ void strip4(const float* __restrict__ v,
                                       const float* __restrict__ t,
                                       const float* __restrict__ g,
                                       int c0, int r0, int ry1, int ry2,
                                       int cx1, int cx2, float w0, float w1,
                                       float& s_in, float& s_gr) {
    // A[plane][row i][col j]; col j=0 is c0-1 .. j=5 is c0+4
    float A[3][PRX + 2][6];
    const float* P[3] = { v, t, g };
    if (MASK) {
        const int c4 = min(max(c0, 0), WW - 4);   // aligned float4 base (safe)
        const int cl = max(c0 - 1, 0);
        const int cr = min(c0 + 4, WW - 1);
        bool okc[6];
        #pragma unroll
        for (int j = 0; j < 6; ++j) {
            const int cc = c0 - 1 + j;
            okc[j] = (cc >= cx1) && (cc < cx2);
        }
        #pragma unroll
        for (int i = 0; i < PRX + 2; ++i) {
            const int rr  = r0 - 1 + i;
            const bool rok = (rr >= ry1) && (rr < ry2);
            const int rb  = min(max(rr, 0), HH - 1) * WW;
            #pragma unroll
            for (int p = 0; p < 3; ++p) {
                const float4 f = *(const float4*)(P[p] + rb + c4);
                const float eL = P[p][rb + cl];
                const float eR = P[p][rb + cr];
                A[p][i][0] = (rok && okc[0]) ? eL  : 0.0f;
                A[p][i][1] = (rok && okc[1]) ? f.x : 0.0f;
                A[p][i][2] = (rok && okc[2]) ? f.y : 0.0f;
                A[p][i][3] = (rok && okc[3]) ? f.z : 0.0f;
                A[p][i][4] = (rok && okc[4]) ? f.w : 0.0f;
                A[p][i][5] = (rok && okc[5]) ? eR  : 0.0f;
            }
        }
        #pragma unroll
        for (int s = 0; s < PRX; ++s) {
            const int rc = r0 + s;                       // center row
            const bool rcin = (rc >= ry1) && (rc < ry2);
            #pragma unroll
            for (int c = 0; c < 4; ++c) {
                float gx[3], gy[3];
                #pragma unroll
                for (int p = 0; p < 3; ++p) {
                    gx[p] = (A[p][s][c + 2] - A[p][s][c])
                          + 2.0f * (A[p][s + 1][c + 2] - A[p][s + 1][c])
                          + (A[p][s + 2][c + 2] - A[p][s + 2][c]);
                    gy[p] = (A[p][s][c] + 2.0f * A[p][s][c + 1] + A[p][s][c + 2])
                          - (A[p][s + 2][c] + 2.0f * A[p][s + 2][c + 1] + A[p][s + 2][c + 2]);
                }
                const float sv  = fabsf(gx[0]) + fabsf(gy[0]);
                const float sg  = fabsf(gx[2]) + fabsf(gy[2]);
                const float gxm = w0 * gx[0] + w1 * gx[1];
                const float gym = w0 * gy[0] + w1 * gy[1];
                const float sm  = fabsf(gxm) + fabsf(gym);
                const float vc  = A[0][s + 1][c + 1];
                const float tc  = A[1][s + 1][c + 1];
                const float gc  = A[2][s + 1][c + 1];
                const float mc  = w0 * vc + w1 * tc;
                const float inb = (rcin && okc[c + 1]) ? 1.0f : 0.0f;
                s_gr += inb * fabsf(sg - fmaxf(sv, sm));
                s_in += inb * fabsf(gc - fmaxf(vc, mc));
            }
        }
    } else {
        // ---- fast path: straight loads, identical expression tree, no selects
        #pragma unroll
        for (int i = 0; i < PRX + 2; ++i) {
            const int rb = (r0 - 1 + i) * WW;
            #pragma unroll
            for (int p = 0; p < 3; ++p) {
                const float4 f = *(const float4*)(P[p] + rb + c0);
                A[p][i][0] = P[p][rb + c0 - 1];
                A[p][i][1] = f.x;
                A[p][i][2] = f.y;
                A[p][i][3] = f.z;
                A[p][i][4] = f.w;
                A[p][i][5] = P[p][rb + c0 + 4];
            }
        }
        #pragma unroll
        for (int s = 0; s < PRX; ++s) {
            #pragma unroll
            for (int c = 0; c < 4; ++c) {
                float gx[3], gy[3];
                #pragma unroll
                for (int p = 0; p < 3; ++p) {
                    gx[p] = (A[p][s][c + 2] - A[p][s][c])
                          + 2.0f * (A[p][s + 1][c + 2] - A[p][s + 1][c])
                          + (A[p][s + 2][c + 2] - A[p][s + 2][c]);
                    gy[p] = (A[p][s][c] + 2.0f * A[p][s][c + 1] + A[p][s][c + 2])
                          - (A[p][s + 2][c] + 2.0f * A[p][s + 2][c + 1] + A[p][s + 2][c + 2]);
                }
                const float sv  = fabsf(gx[0]) + fabsf(gy[0]);
                const float sg  = fabsf(gx[2]) + fabsf(gy[2]);
                const float gxm = w0 * gx[0] + w1 * gx[1];
                const float gym = w0 * gy[0] + w1 * gy[1];
                const float sm  = fabsf(gxm) + fabsf(gym);
                const float vc  = A[0][s + 1][c + 1];
                const float tc  = A[1][s + 1][c + 1];
                const float gc  = A[2][s + 1][c + 1];
                const float mc  = w0 * vc + w1 * tc;
                s_gr += fabsf(sg - fmaxf(sv, sm));
                s_in += fabsf(gc - fmaxf(vc, mc));
            }
        }
    }
}

// ---------------- Fused main kernel ----------------
// logical blocks [0, GIBLK):          global interior strips (fast path)
// logical blocks [GIBLK, GALL):       global boundary strips (masked path)
// logical blocks [GALL, GALL+XBLKS):  box bands (masked path)
// Every block writes its 2 partial sums to a dedicated slot (no init needed).
__global__ __launch_bounds__(BLK) void kmain(const float* __restrict__ vis,
                                             const float* __restrict__ th,
                                             const float* __restrict__ gen,
                                             const int* __restrict__ label,
                                             float* __restrict__ gpart,
                                             float* __restrict__ xpart) {
    const int t = threadIdx.x;
    // XCD-contiguous logical block id (bijective; see #define block comment)
    const unsigned xcd = blockIdx.x % NXCD;
    const unsigned idx = blockIdx.x / NXCD;
    const unsigned bx  = (xcd < RW ? xcd * (QW + 1)
                                   : RW * (QW + 1) + (xcd - RW) * QW) + idx;
    float s_in = 0.0f, s_gr = 0.0f;
    if (bx < GIBLK) {
        // ---- global interior: gi -> (batch, band, xt), bands/tiles 1..158
        const int gi = bx * BLK + t;
        const int b  = gi / NISLOT;
        const int r  = gi - b * NISLOT;
        if (r < NISTR) {
            const int xt   = 1 + r % NIT;
            const int band = 1 + r / NIT;
            strip4<false>(vis + b * HWSZ, th + b * HWSZ, gen + b * HWSZ,
                          4 * xt, 4 * band, 0, HH, 0, WW, 0.5f, 0.5f,
                          s_in, s_gr);
        }
        reduce2_write(s_in, s_gr, gpart + bx * 2);
    } else if (bx < GALL) {
        // ---- global boundary: 636 strips/batch on the image frame
        const int q = (bx - GIBLK) * BLK + t;
        const int b = q / NBSLOT;
        const int r = q - b * NBSLOT;
        if (r < NBSTR) {
            int band, xt;
            if (r < 160)      { band = 0;   xt = r; }
            else if (r < 320) { band = 159; xt = r - 160; }
            else if (r < 478) { xt = 0;     band = 1 + (r - 320); }
            else              { xt = 159;   band = 1 + (r - 478); }
            strip4<true>(vis + b * HWSZ, th + b * HWSZ, gen + b * HWSZ,
                         4 * xt, 4 * band, 0, HH, 0, WW, 0.5f, 0.5f,
                         s_in, s_gr);
        }
        reduce2_write(s_in, s_gr, gpart + bx * 2);
    } else {
        // ---- box phase: block = (box, slot); wave w covers bands slot+w*SLOTS,
        //      stepping 2*SLOTS bands; 64-lane x 4-col (256-wide) column tiles.
        const int q    = bx - GALL;
        const int box  = q / SLOTS;
        const int slot = q % SLOTS;
        const int b    = box / NLB;
        const int w    = t >> 6;
        const int lane = t & 63;
        const int* lb  = label + box * 5;
        const int x1 = lb[1], y1 = lb[2], x2 = lb[3], y2 = lb[4];
        const int x1a = x1 & ~3;   // aligned start; cols < x1 are masked
        const float* v  = vis + b * HWSZ;
        const float* tp = th  + b * HWSZ;
        const float* g  = gen + b * HWSZ;
        for (int r0 = y1 + (slot + w * SLOTS) * PRX; r0 < y2;
             r0 += 2 * SLOTS * PRX)
            for (int cb = x1a; cb < x2; cb += 64 * 4) {
                const int c0 = cb + 4 * lane;
                // lanes fully right of the box contribute exactly 0 -> skip
                if (c0 < x2)
                    strip4<true>(v, tp, g, c0, r0, y1, y2, x1, x2,
                                 0.3f, 0.7f, s_in, s_gr);
            }
        reduce2_write(s_in, s_gr, xpart + q * 2);
    }
}

// ---------------- Finalize: reduce partials, compute all 7 outputs ----------
// out layout (flat, return order): loss_ss[4], loss_global[4], loss_label[4],
//                                  loss_in[4], loss_grad[4], ls[4], lin[4]
__global__ __launch_bounds__(256) void kfin(const float* __restrict__ gpart,
                                            const float* __restrict__ xpart,
                                            const int* __restrict__ label,
                                            const float* __restrict__ bptr,
                                            const float* __restrict__ cptr,
                                            float* __restrict__ out) {
    const int t = threadIdx.x;
    __shared__ float Sin[BB], Sgr[BB];
    __shared__ float Ls[BB * NLB], L1[BB * NLB];
    // global partial reduce: wave w = batch w
    //   interior blocks [w*NIBPB, (w+1)*NIBPB) + boundary [GIBLK+w*NBBPB, +NBBPB)
    {
        const int w = t >> 6, l = t & 63;
        float a = 0.0f, gr = 0.0f;
        for (int j = l; j < NIBPB; j += 64) {
            a  += gpart[(w * NIBPB + j) * 2 + 0];
            gr += gpart[(w * NIBPB + j) * 2 + 1];
        }
        if (l < NBBPB) {
            const int idx = GIBLK + w * NBBPB + l;
            a  += gpart[idx * 2 + 0];
            gr += gpart[idx * 2 + 1];
        }
        #pragma unroll
        for (int off = 32; off > 0; off >>= 1) {
            a  += __shfl_down(a, off);
            gr += __shfl_down(gr, off);
        }
        if (l == 0) { Sin[w] = a; Sgr[w] = gr; }
    }
    // per-box reduce over band slots + area/valid normalization
    if (t < BB * NLB) {
        float si = 0.0f, sg = 0.0f;
        #pragma unroll
        for (int s = 0; s < SLOTS; ++s) {
            si += xpart[(t * SLOTS + s) * 2 + 0];
            sg += xpart[(t * SLOTS + s) * 2 + 1];
        }
        const int* lb = label + t * 5;
        const int x1 = lb[1], y1 = lb[2], x2 = lb[3], y2 = lb[4];
        const bool valid = !((x1 == 0) && (y1 == 0) && (x2 == 0) && (y2 == 0));
        const float area = (float)((y2 - y1) * (x2 - x1));  // * C, C==1
        const float safe_area = fmaxf(area, 1.0f);
        const float vv = valid ? 1.0f : 0.0f;
        Ls[t] = sg / safe_area * vv;   // Lssim: gradient term
        L1[t] = si / safe_area * vv;   // L1loss: intensity term
    }
    __syncthreads();
    if (t < BB) {
        const float alpha = bptr[0];
        const float beta  = cptr[0];
        float cnt = 0.0f, sls = 0.0f, slin = 0.0f;
        for (int nl = 0; nl < NLB; nl++) {
            const float a = Ls[t * NLB + nl];
            const float l = L1[t * NLB + nl];
            if (a != 0.0f || l != 0.0f) cnt += 1.0f;
            sls  += a;
            slin += l;
        }
        const float safe_cnt = fmaxf(cnt, 1.0f);
        const float ls  = (cnt > 0.0f) ? (sls  / safe_cnt) : 0.0f;
        const float lin = (cnt > 0.0f) ? (slin / safe_cnt) : 0.0f;
        const float loss_label = (1.0f - beta) * ls + beta * lin;
        const float loss_in    = Sin[t] * (1.0f / (float)HWSZ);
        const float loss_grad  = Sgr[t] * (1.0f / (float)HWSZ);
        const float loss_global = alpha * loss_in + (1.0f - alpha) * loss_grad;
        out[0      + t] = 0.0f;          // loss_ss
        out[BB     + t] = loss_global;
        out[2 * BB + t] = loss_label;
        out[3 * BB + t] = loss_in;
        out[4 * BB + t] = loss_grad;
        out[5 * BB + t] = ls;
        out[6 * BB + t] = lin;
    }
}

extern "C" void kernel_launch(void* const* d_in, const int* in_sizes, int n_in,
                              void* d_out, int out_size, void* d_ws, size_t ws_size,
                              hipStream_t stream) {
    const float* bptr  = (const float*)d_in[0];
    const float* cptr  = (const float*)d_in[1];
    const float* vis   = (const float*)d_in[2];
    // d_in[3] = image_ir (unused by the reference)
    const float* gen   = (const float*)d_in[4];
    const int*   label = (const int*)d_in[5];
    const float* th    = (const float*)d_in[6];
    float* out = (float*)d_out;

    float* gpart = (float*)d_ws;            // GALL*2 floats
    float* xpart = gpart + GALL * 2;        // XBLKS*2 floats
    // Every slot is written unconditionally by its block — no memset needed.

    kmain<<<NWG, BLK, 0, stream>>>(vis, th, gen, label, gpart, xpart);
    kfin<<<1, 256, 0, stream>>>(gpart, xpart, label, bptr, cptr, out);
}